// Round 4
// baseline (248.750 us; speedup 1.0000x reference)
//
#include <hip/hip_runtime.h>
#include <hip/hip_bf16.h>

typedef unsigned short u16;
typedef unsigned int   u32;

typedef __attribute__((ext_vector_type(8))) __bf16 bf16x8;
typedef __attribute__((ext_vector_type(4))) float  f32x4;

#define NN 4096
#define DD 128
#define EPS 1e-12f

#define KS 4            // split-K factor for gemm1
#define BM 32           // rows per block
#define BK 128          // k per stage
#define KPER (NN / KS)  // 1024
#define LDK 136         // padded LDS row stride (u16)

#define SBLK 64         // sort blocks (big chunks -> cheap per-block bin flush)

static __device__ __forceinline__ u16 f2bf(float f) {
    union { float f; u32 u; } v; v.f = f;
    u32 r = v.u + 0x7fffu + ((v.u >> 16) & 1u);   // round-to-nearest-even
    return (u16)(r >> 16);
}

// ---------------------------------------------------------------------------
// Edge kernel (pure stream now): 32 lanes per edge, 2 edges per wave.
// val[e] = exp(-||A[c]+case-A[t]||).  No atomics, no att matrix.
// ---------------------------------------------------------------------------
__global__ __launch_bounds__(256) void edge_kernel(
    const int* __restrict__ currents, const int* __restrict__ targets,
    const float* __restrict__ A, const float* __restrict__ cases,
    float* __restrict__ val, int E)
{
    int e = blockIdx.x * 8 + (threadIdx.x >> 5);
    if (e >= E) return;
    int l = threadIdx.x & 31;
    int c = currents[e];
    int t = targets[e];
    f32x4 h = *(const f32x4*)(A + (size_t)c * DD + l * 4);
    f32x4 g = *(const f32x4*)(A + (size_t)t * DD + l * 4);
    f32x4 q = __builtin_nontemporal_load((const f32x4*)(cases + (size_t)e * DD + l * 4));
    float d0 = h.x + q.x - g.x;
    float d1 = h.y + q.y - g.y;
    float d2 = h.z + q.z - g.z;
    float d3 = h.w + q.w - g.w;
    float s = d0 * d0 + d1 * d1 + d2 * d2 + d3 * d3;
#pragma unroll
    for (int m = 16; m; m >>= 1) s += __shfl_xor(s, m, 64);
    if (l == 0) val[e] = __expf(-__fsqrt_rn(s));
}

// ---------------------------------------------------------------------------
// Counting-sort phase 1: per-block histogram of targets.
// blk_cnt[blk][t] = #edges with target t in this block's chunk. No atomics
// beyond LDS. Every bin written -> no global memset needed.
// ---------------------------------------------------------------------------
__global__ __launch_bounds__(256) void hist_kernel(
    const int* __restrict__ targets, u32* __restrict__ blk_cnt, int E)
{
    __shared__ u32 h[NN];
    const int blk = blockIdx.x, tid = threadIdx.x;
    const int chunk = (E + SBLK - 1) / SBLK;
    const int lo = blk * chunk, hi = min(E, lo + chunk);
    for (int b = tid; b < NN; b += 256) h[b] = 0;
    __syncthreads();
    for (int i = lo + tid; i < hi; i += 256) atomicAdd(&h[targets[i]], 1u);
    __syncthreads();
    u32* out = blk_cnt + (size_t)blk * NN;
    for (int b = tid; b < NN; b += 256) out[b] = h[b];
}

// ---------------------------------------------------------------------------
// Phase 2a: per-bin exclusive prefix over blocks. One thread per bin.
// blk_base[blk][t] = #edges with target t in earlier blocks. bin_total[t].
// ---------------------------------------------------------------------------
__global__ __launch_bounds__(256) void scanA_kernel(
    const u32* __restrict__ blk_cnt, u32* __restrict__ blk_base,
    u32* __restrict__ bin_total)
{
    int t = blockIdx.x * 256 + threadIdx.x;   // grid 16 x 256 = 4096
    u32 run = 0;
#pragma unroll 4
    for (int b = 0; b < SBLK; ++b) {
        u32 v = blk_cnt[(size_t)b * NN + t];
        blk_base[(size_t)b * NN + t] = run;
        run += v;
    }
    bin_total[t] = run;
}

// ---------------------------------------------------------------------------
// Phase 2b: exclusive scan of bin_total -> row_start[0..4096].
// ---------------------------------------------------------------------------
__global__ __launch_bounds__(256) void scanB_kernel(
    const u32* __restrict__ bin_total, u32* __restrict__ row_start)
{
    __shared__ u32 lsum[256];
    int tid = threadIdx.x;
    u32 loc[16]; u32 s = 0;
#pragma unroll
    for (int k = 0; k < 16; ++k) { loc[k] = bin_total[tid * 16 + k]; s += loc[k]; }
    lsum[tid] = s;
    __syncthreads();
    for (int d = 1; d < 256; d <<= 1) {
        u32 v = (tid >= d) ? lsum[tid - d] : 0u;
        __syncthreads();
        lsum[tid] += v;
        __syncthreads();
    }
    u32 base = lsum[tid] - s;   // exclusive
#pragma unroll
    for (int k = 0; k < 16; ++k) { row_start[tid * 16 + k] = base; base += loc[k]; }
    if (tid == 255) row_start[NN] = lsum[255];
}

// ---------------------------------------------------------------------------
// Phase 3: scatter (c,val) into target-sorted pairs array. Slot offsets via
// LDS counters only; bases precomputed -> ZERO global atomics.
// Must use the same chunking as hist_kernel.
// ---------------------------------------------------------------------------
__global__ __launch_bounds__(256) void scatter_kernel(
    const int* __restrict__ currents, const int* __restrict__ targets,
    const float* __restrict__ val, const u32* __restrict__ blk_base,
    const u32* __restrict__ row_start, uint2* __restrict__ pairs, int E)
{
    __shared__ u32 run[NN];
    const int blk = blockIdx.x, tid = threadIdx.x;
    const int chunk = (E + SBLK - 1) / SBLK;
    const int lo = blk * chunk, hi = min(E, lo + chunk);
    for (int b = tid; b < NN; b += 256) run[b] = 0;
    __syncthreads();
    const u32* bb = blk_base + (size_t)blk * NN;
    for (int i = lo + tid; i < hi; i += 256) {
        int t = targets[i];
        int c = currents[i];
        float v = val[i];
        u32 idx = atomicAdd(&run[t], 1u);
        u32 slot = row_start[t] + bb[t] + idx;
        pairs[slot] = make_uint2((u32)c, __float_as_uint(v));
    }
}

// ---------------------------------------------------------------------------
// SpMM: one block (128 threads) per output row t.
//   out[t][d] = (sum_edges val * feat[c][d]) / (sum val + EPS) + feat[t][d]
// feat is 2 MB -> L2-resident; gathers run at L2 BW.
// ---------------------------------------------------------------------------
__global__ __launch_bounds__(128) void spmm_kernel(
    const uint2* __restrict__ pairs, const u32* __restrict__ row_start,
    const float* __restrict__ feat, float* __restrict__ out)
{
    __shared__ u32   lc[128];
    __shared__ float lv[128];
    const int t = blockIdx.x, tid = threadIdx.x;
    const u32 s = row_start[t], e_ = row_start[t + 1];
    float acc = 0.f, nsum = 0.f;
    for (u32 s0 = s; s0 < e_; s0 += 128) {
        int n = (int)min(128u, e_ - s0);
        if (tid < n) {
            uint2 p = pairs[s0 + tid];
            lc[tid] = p.x;
            lv[tid] = __uint_as_float(p.y);
        }
        __syncthreads();
#pragma unroll 4
        for (int j = 0; j < n; ++j) {
            acc = fmaf(lv[j], feat[(size_t)lc[j] * DD + tid], acc);
            nsum += lv[j];
        }
        __syncthreads();
    }
    float f = feat[(size_t)t * DD + tid];
    out[(size_t)t * DD + tid] = acc / (nsum + EPS) + f;
}

// ---------------------------------------------------------------------------
// Transpose+convert: in [4096][128] fp32 -> out [128][4096] bf16
// ---------------------------------------------------------------------------
__global__ __launch_bounds__(256) void transpose_to_bf16(
    const float* __restrict__ in, u16* __restrict__ out)
{
    __shared__ __align__(16) u16 lds[128][40];
    const int k0 = blockIdx.x * 32;
    const int t = threadIdx.x;
#pragma unroll
    for (int i = 0; i < 4; ++i) {
        int f  = t + 256 * i;
        int kr = f >> 5;
        int n0 = (f & 31) * 4;
        float4 v = *(const float4*)(in + (size_t)(k0 + kr) * DD + n0);
        lds[n0 + 0][kr] = f2bf(v.x);
        lds[n0 + 1][kr] = f2bf(v.y);
        lds[n0 + 2][kr] = f2bf(v.z);
        lds[n0 + 3][kr] = f2bf(v.w);
    }
    __syncthreads();
    int n = t >> 1, h = t & 1;
    uint4 v0 = *(const uint4*)&lds[n][h * 16];
    uint4 v1 = *(const uint4*)&lds[n][h * 16 + 8];
    *(uint4*)(out + (size_t)n * NN + k0 + h * 16)     = v0;
    *(uint4*)(out + (size_t)n * NN + k0 + h * 16 + 8) = v1;
}

// ---------------------------------------------------------------------------
// Split-K skinny GEMM (W @ acts): part[ks] = W[m0:m0+32, ks*1024:+1024] @ B
// W fp32 (converted to bf16 in staging, nontemporal), BT bf16 [128][4096].
// 1-deep register pipeline. 512 threads = 8 waves.
// ---------------------------------------------------------------------------
__global__ __launch_bounds__(512, 4) void gemm_splitk(
    const float* __restrict__ Amat,   // [4096][4096] fp32
    const u16*   __restrict__ BT,     // [128][4096] bf16 (B^T)
    float* __restrict__ part)         // [KS][4096][128]
{
    __shared__ __align__(16) u16 As[BM * LDK];
    __shared__ __align__(16) u16 Bs[DD * LDK];

    const int m0   = blockIdx.x * BM;
    const int ks   = blockIdx.y;
    const int kbeg = ks * KPER;
    const int t    = threadIdx.x;
    const int wave = t >> 6;
    const int lane = t & 63;
    const int quad = lane >> 4;
    const int l16  = lane & 15;

    const int ar = t >> 4;   // 0..31 (A row)
    const int aq = t & 15;
    const int bn = t >> 2;   // 0..127 (B row)
    const int bq = t & 3;

    const float* Ap = Amat + (size_t)(m0 + ar) * NN + kbeg + aq * 4;
    const u16*   Bp = BT   + (size_t)bn * NN + kbeg + bq * 32;

    f32x4 va0 = __builtin_nontemporal_load((const f32x4*)Ap);
    f32x4 va1 = __builtin_nontemporal_load((const f32x4*)(Ap + 64));
    uint4 vb0 = *(const uint4*)(Bp);
    uint4 vb1 = *(const uint4*)(Bp + 8);
    uint4 vb2 = *(const uint4*)(Bp + 16);
    uint4 vb3 = *(const uint4*)(Bp + 24);

    f32x4 acc0 = {0.f, 0.f, 0.f, 0.f};
    f32x4 acc1 = {0.f, 0.f, 0.f, 0.f};

    for (int kk = 0; kk < KPER; kk += BK) {
        ushort4 u0, u1;
        u0.x = f2bf(va0.x); u0.y = f2bf(va0.y); u0.z = f2bf(va0.z); u0.w = f2bf(va0.w);
        u1.x = f2bf(va1.x); u1.y = f2bf(va1.y); u1.z = f2bf(va1.z); u1.w = f2bf(va1.w);
        *(ushort4*)&As[ar * LDK + aq * 4]      = u0;
        *(ushort4*)&As[ar * LDK + aq * 4 + 64] = u1;
        *(uint4*)&Bs[bn * LDK + bq * 32]      = vb0;
        *(uint4*)&Bs[bn * LDK + bq * 32 + 8]  = vb1;
        *(uint4*)&Bs[bn * LDK + bq * 32 + 16] = vb2;
        *(uint4*)&Bs[bn * LDK + bq * 32 + 24] = vb3;
        __syncthreads();

        if (kk + BK < KPER) {
            int k1 = kk + BK;
            va0 = __builtin_nontemporal_load((const f32x4*)(Ap + k1));
            va1 = __builtin_nontemporal_load((const f32x4*)(Ap + k1 + 64));
            vb0 = *(const uint4*)(Bp + k1);
            vb1 = *(const uint4*)(Bp + k1 + 8);
            vb2 = *(const uint4*)(Bp + k1 + 16);
            vb3 = *(const uint4*)(Bp + k1 + 24);
        }

#pragma unroll
        for (int k2 = 0; k2 < 4; ++k2) {
            bf16x8 a0 = *(const bf16x8*)&As[l16 * LDK + k2 * 32 + quad * 8];
            bf16x8 a1 = *(const bf16x8*)&As[(16 + l16) * LDK + k2 * 32 + quad * 8];
            bf16x8 b  = *(const bf16x8*)&Bs[(wave * 16 + l16) * LDK + k2 * 32 + quad * 8];
            acc0 = __builtin_amdgcn_mfma_f32_16x16x32_bf16(a0, b, acc0, 0, 0, 0);
            acc1 = __builtin_amdgcn_mfma_f32_16x16x32_bf16(a1, b, acc1, 0, 0, 0);
        }
        __syncthreads();
    }

    float* P = part + (size_t)ks * NN * DD;
#pragma unroll
    for (int r = 0; r < 4; ++r) {
        int row0 = m0 + quad * 4 + r;
        int col  = wave * 16 + l16;
        P[(size_t)row0 * DD + col]        = acc0[r];
        P[(size_t)(row0 + 16) * DD + col] = acc1[r];
    }
}

// ---------------------------------------------------------------------------
// feat = sum of KS partials
// ---------------------------------------------------------------------------
__global__ __launch_bounds__(256) void combine_feat(
    const float* __restrict__ part, float* __restrict__ feat)
{
    int i = blockIdx.x * 256 + threadIdx.x;
    const float4* p = (const float4*)part;
    const int S = NN * DD / 4;
    float4 a = p[i], b = p[i + S], c = p[i + 2 * S], d = p[i + 3 * S];
    float4 s;
    s.x = (a.x + b.x) + (c.x + d.x);
    s.y = (a.y + b.y) + (c.y + d.y);
    s.z = (a.z + b.z) + (c.z + d.z);
    s.w = (a.w + b.w) + (c.w + d.w);
    ((float4*)feat)[i] = s;
}

// ---------------------------------------------------------------------------
extern "C" void kernel_launch(void* const* d_in, const int* in_sizes, int n_in,
                              void* d_out, int out_size, void* d_ws, size_t ws_size,
                              hipStream_t stream)
{
    const int*   currents = (const int*)d_in[0];
    const int*   targets  = (const int*)d_in[1];
    const float* acts     = (const float*)d_in[2];   // [4096][128]
    const float* cases    = (const float*)d_in[3];   // [E][128]
    const float* W        = (const float*)d_in[4];   // [4096][4096]
    float*       out      = (float*)d_out;           // [4096][128]
    const int E = in_sizes[0];

    // workspace layout (all 16B-aligned)
    char* ws = (char*)d_ws;
    uint2* pairs     = (uint2*)ws;                                   // 8 MB
    float* val       = (float*)(ws + (size_t)8  * 1024 * 1024);     // 4 MB
    float* part      = (float*)(ws + (size_t)12 * 1024 * 1024);     // 8 MB
    float* feat      = (float*)(ws + (size_t)20 * 1024 * 1024);     // 2 MB
    u16*   BT1       = (u16*)  (ws + (size_t)22 * 1024 * 1024);     // 1 MB
    u32*   blk_cnt   = (u32*)  (ws + (size_t)23 * 1024 * 1024);     // 1 MB
    u32*   blk_base  = (u32*)  (ws + (size_t)24 * 1024 * 1024);     // 1 MB
    u32*   bin_total = (u32*)  (ws + (size_t)25 * 1024 * 1024);     // 16 KB
    u32*   row_start = bin_total + NN;                               // 16 KB + 4

    // --- target-sort bookkeeping (tiny, atomic-free) ---
    hist_kernel <<<SBLK, 256, 0, stream>>>(targets, blk_cnt, E);
    scanA_kernel<<<NN / 256, 256, 0, stream>>>(blk_cnt, blk_base, bin_total);
    scanB_kernel<<<1, 256, 0, stream>>>(bin_total, row_start);

    // BT1 = bf16(acts^T)
    transpose_to_bf16<<<128, 256, 0, stream>>>(acts, BT1);

    // edge values (pure stream, no atomics)
    edge_kernel<<<(E + 7) / 8, 256, 0, stream>>>(currents, targets, acts, cases,
                                                 val, E);

    // sort (c, val) by target
    scatter_kernel<<<SBLK, 256, 0, stream>>>(currents, targets, val, blk_base,
                                             row_start, pairs, E);

    // feat = W @ acts
    gemm_splitk<<<dim3(NN / BM, KS), 512, 0, stream>>>(W, BT1, part);
    combine_feat<<<NN * DD / 4 / 256, 256, 0, stream>>>(part, feat);

    // out = normalized SpMM + feat
    spmm_kernel<<<NN, 128, 0, stream>>>(pairs, row_start, feat, out);
}